// Round 10
// baseline (28.411 us; speedup 1.0000x reference)
//
#include <hip/hip_runtime.h>
#include <math.h>

// Chamfer loss, B=8, N=M=4096, D=3, fp32. Two kernels (r7 structure).
// k1: 256 blocks = (dir, batch, 256-query chunk), T=1024 (16 waves, 4/SIMD).
//     Full 4096-pt target cloud staged in LDS as (t0,t1,t2,|t|^2) [64 KB]
//     (r7 staging: lane-consecutive ds_write_b128 = conflict-free; r9's
//     64B-lane-stride variant was a ~16-way write conflict -- reverted).
//     Thread (qrow=tid&15, slice=tid>>4): 16 queries, scans 64-target slice.
//     KPT=16: each ds_read_b128 pair feeds 112 VALU (vs 56 at KPT=8) so
//     LDS latency at unroll boundaries hides under arithmetic.
//     d' = |t|^2 - 2 q.t ; v_min3_f32 folds the pair-min (3.5 ops/pair).
//     |q|^2 + clamp deferred past the cross-slice min.
// k2: one wave sums the 256 weighted per-block partials (float4 loads).

constexpr int BATCH = 8;
constexpr int NP    = 4096;   // points per cloud
constexpr int T     = 1024;   // threads per block (16 waves, 4/SIMD)
constexpr int QPB   = 256;    // queries per block
constexpr int KPT   = 16;     // queries per thread
constexpr int S     = 64;     // target slices
constexpr int TPS   = 64;     // targets per slice

__global__ __launch_bounds__(T, 4) void chamfer_main(
    const float* __restrict__ x, const float* __restrict__ y,
    const float* __restrict__ w, float* __restrict__ ps)
{
    const int bid = blockIdx.x;          // dir(1b) | b(3b) | qc(4b)
    const int dir = bid >> 7;
    const int b   = (bid >> 4) & 7;
    const int qc  = bid & 15;

    const float* q = dir ? y : x;
    const float* t = dir ? x : y;

    __shared__ float4 ty[NP];            // 64 KB target stage
    __shared__ float  pmin[S / 4][QPB];  // 16 KB cross-slice mins (16 rows)
    __shared__ float  qn[QPB];           // |q|^2 per query
    __shared__ float  rsum[T / 64];

    const int tid = threadIdx.x;

    // stage all 4096 targets of batch b (r7 proven pattern:
    // strided scalar global reads + lane-consecutive b128 LDS writes)
    const float* tb = t + (size_t)b * NP * 3;
    for (int j = tid; j < NP; j += T) {
        float t0 = tb[3 * j + 0];
        float t1 = tb[3 * j + 1];
        float t2 = tb[3 * j + 2];
        ty[j] = make_float4(t0, t1, t2, fmaf(t0, t0, fmaf(t1, t1, t2 * t2)));
    }

    // this thread's 16 queries (48 consecutive floats, 16B-aligned)
    const int qrow  = tid & 15;
    const int slice = tid >> 4;          // [0,64); wave = 4 slices
    const int n0 = b * NP + qc * QPB + qrow * KPT;
    const float4* qb = reinterpret_cast<const float4*>(q + (size_t)n0 * 3);
    float qf[48];
    #pragma unroll
    for (int i = 0; i < 12; ++i) {
        float4 v = qb[i];
        qf[4 * i + 0] = v.x; qf[4 * i + 1] = v.y;
        qf[4 * i + 2] = v.z; qf[4 * i + 3] = v.w;
    }
    float xn[KPT][3], mn[KPT];
    #pragma unroll
    for (int k = 0; k < KPT; ++k) {
        float c0 = qf[3 * k], c1 = qf[3 * k + 1], c2 = qf[3 * k + 2];
        if (slice == 0)
            qn[qrow * KPT + k] = fmaf(c0, c0, fmaf(c1, c1, c2 * c2));
        xn[k][0] = -2.0f * c0;
        xn[k][1] = -2.0f * c1;
        xn[k][2] = -2.0f * c2;
        mn[k] = INFINITY;
    }

    __syncthreads();

    // min over this slice's targets of d' = |t|^2 - 2 q.t
    const int j0 = slice * TPS;
    #pragma unroll 2
    for (int j = j0; j < j0 + TPS; j += 2) {
        float4 ta = ty[j];               // 4 distinct addrs/wave (broadcast)
        float4 tc = ty[j + 1];
        #pragma unroll
        for (int k = 0; k < KPT; ++k) {
            float da = fmaf(xn[k][0], ta.x,
                       fmaf(xn[k][1], ta.y, fmaf(xn[k][2], ta.z, ta.w)));
            float db = fmaf(xn[k][0], tc.x,
                       fmaf(xn[k][1], tc.y, fmaf(xn[k][2], tc.z, tc.w)));
            float m;
            asm("v_min3_f32 %0, %1, %2, %3"
                : "=v"(m) : "v"(mn[k]), "v"(da), "v"(db));
            mn[k] = m;                   // 3.5 VALU ops per pair
        }
    }

    // intra-wave fold of the 4 slices (lanes l^32: slice+-2, l^16: slice+-1)
    #pragma unroll
    for (int k = 0; k < KPT; ++k) {
        mn[k] = fminf(mn[k], __shfl_xor(mn[k], 32, 64));
        mn[k] = fminf(mn[k], __shfl_xor(mn[k], 16, 64));
    }
    if ((slice & 3) == 0) {              // lanes 0-15 of each wave
        #pragma unroll
        for (int k = 0; k < KPT; ++k)
            pmin[slice >> 2][qrow * KPT + k] = mn[k];
    }
    __syncthreads();

    float val = 0.0f;
    if (tid < QPB) {                     // thread tid owns query tid
        float m = pmin[0][tid];
        #pragma unroll
        for (int s = 1; s < S / 4; ++s) m = fminf(m, pmin[s][tid]);
        val = fmaxf(qn[tid] + m, 0.0f);  // clamp after full min
    }

    // fixed-order block sum (other waves contribute 0)
    for (int off = 32; off; off >>= 1) val += __shfl_down(val, off, 64);
    if ((tid & 63) == 0) rsum[tid >> 6] = val;
    __syncthreads();
    if (tid == 0) {
        float s = 0.0f;
        #pragma unroll
        for (int i = 0; i < T / 64; ++i) s += rsum[i];
        ps[bid] = s * w[b] * (1.0f / ((float)NP * (float)BATCH));
    }
}

__global__ __launch_bounds__(64) void chamfer_final(
    const float* __restrict__ ps, float* __restrict__ out)
{
    const int l = threadIdx.x;           // one wave
    float4 v = reinterpret_cast<const float4*>(ps)[l];
    float s = (v.x + v.y) + (v.z + v.w);
    for (int off = 32; off; off >>= 1) s += __shfl_down(s, off, 64);
    if (l == 0) out[0] = s;
}

extern "C" void kernel_launch(void* const* d_in, const int* in_sizes, int n_in,
                              void* d_out, int out_size, void* d_ws, size_t ws_size,
                              hipStream_t stream) {
    const float* x = (const float*)d_in[0];   // (8, 4096, 3)
    const float* y = (const float*)d_in[1];   // (8, 4096, 3)
    const float* w = (const float*)d_in[2];   // (8,)
    float* out = (float*)d_out;
    float* ps  = (float*)d_ws;                // 256 floats

    chamfer_main<<<256, T, 0, stream>>>(x, y, w, ps);
    chamfer_final<<<1, 64, 0, stream>>>(ps, out);
}